// Round 11
// baseline (651.696 us; speedup 1.0000x reference)
//
#include <hip/hip_runtime.h>

#define NN 50000
#define EE 800000
#define GG 64
#define CC 8

#define NBKT 196      // ceil(50000/256) node buckets of 256
#define NCHK 782      // edge chunks = grid of k0 (1024 edges each)
#define CHUNK 1024
#define CAP 8192      // max edges per bucket (mean 4082)
#define NB4G 12500    // agg grids: NN/4

// done-ticket for fused pool+sigmoid (module global: zero at load, reset after use -> replay-safe)
__device__ unsigned g_done = 0;

__device__ __forceinline__ float lrelu(float z) { return fmaxf(z, 0.2f * z); }
__device__ __forceinline__ unsigned short f2bf(float v) {
    unsigned u = __float_as_uint(v);
    return (unsigned short)((u + 0x7FFFu + ((u >> 16) & 1u)) >> 16);  // RNE
}
__device__ __forceinline__ float bf2f(unsigned short b) {
    return __uint_as_float(((unsigned)b) << 16);
}

// ---------------- k0: layer-1 matmul (CSR-independent) fused with edge histogram ----------------

__global__ __launch_bounds__(256) void k0_mm11_hist(const float* __restrict__ x, const float* __restrict__ W,
                                                    const float* __restrict__ avs, const float* __restrict__ avd,
                                                    unsigned short* __restrict__ h, float* __restrict__ as_,
                                                    float* __restrict__ ad_, const int* __restrict__ dst,
                                                    int* __restrict__ G) {
    __shared__ float xT[11 * 68];
    __shared__ float Wl[11 * 64];
    __shared__ float avl[64], adl[64];
    __shared__ int hist[NBKT];
    int t = threadIdx.x;
    int nbase = blockIdx.x * 64;
    for (int idx = t; idx < 11 * 64; idx += 256) Wl[idx] = W[idx];
    if (t < 64) { avl[t] = avs[t]; adl[t] = avd[t]; }
    for (int idx = t; idx < 64 * 11; idx += 256) {
        int n = idx / 11, k = idx - n * 11;
        int gn = nbase + n;
        if (gn >= NN) gn = NN - 1;
        xT[k * 68 + n] = x[gn * 11 + k];
    }
    for (int i = t; i < NBKT; i += 256) hist[i] = 0;
    __syncthreads();
    int f0 = (t & 15) * 4;
    int n0 = (t >> 4) * 4;
    float a00=0,a01=0,a02=0,a03=0, a10=0,a11=0,a12=0,a13=0;
    float a20=0,a21=0,a22=0,a23=0, a30=0,a31=0,a32=0,a33=0;
#pragma unroll
    for (int k = 0; k < 11; k++) {
        float4 xv = *(const float4*)&xT[k * 68 + n0];
        float4 wv = *(const float4*)&Wl[k * 64 + f0];
        a00 += xv.x * wv.x; a01 += xv.x * wv.y; a02 += xv.x * wv.z; a03 += xv.x * wv.w;
        a10 += xv.y * wv.x; a11 += xv.y * wv.y; a12 += xv.y * wv.z; a13 += xv.y * wv.w;
        a20 += xv.z * wv.x; a21 += xv.z * wv.y; a22 += xv.z * wv.z; a23 += xv.z * wv.w;
        a30 += xv.w * wv.x; a31 += xv.w * wv.y; a32 += xv.w * wv.z; a33 += xv.w * wv.w;
    }
    float4 av = *(const float4*)&avl[f0];
    float4 dv = *(const float4*)&adl[f0];
    float vs[4], vd[4];
    vs[0] = a00*av.x + a01*av.y + a02*av.z + a03*av.w;
    vs[1] = a10*av.x + a11*av.y + a12*av.z + a13*av.w;
    vs[2] = a20*av.x + a21*av.y + a22*av.z + a23*av.w;
    vs[3] = a30*av.x + a31*av.y + a32*av.z + a33*av.w;
    vd[0] = a00*dv.x + a01*dv.y + a02*dv.z + a03*dv.w;
    vd[1] = a10*dv.x + a11*dv.y + a12*dv.z + a13*dv.w;
    vd[2] = a20*dv.x + a21*dv.y + a22*dv.z + a23*dv.w;
    vd[3] = a30*dv.x + a31*dv.y + a32*dv.z + a33*dv.w;
#pragma unroll
    for (int o = 1; o < 16; o <<= 1) {
#pragma unroll
        for (int ni = 0; ni < 4; ni++) {
            vs[ni] += __shfl_xor(vs[ni], o);
            vd[ni] += __shfl_xor(vd[ni], o);
        }
    }
    ushort4* h4 = (ushort4*)h;
    int nn0 = nbase + n0;
    float rows[4][4] = {{a00,a01,a02,a03},{a10,a11,a12,a13},{a20,a21,a22,a23},{a30,a31,a32,a33}};
#pragma unroll
    for (int ni = 0; ni < 4; ni++) {
        if (nn0 + ni < NN) {
            ushort4 pv;
            pv.x = f2bf(rows[ni][0]); pv.y = f2bf(rows[ni][1]);
            pv.z = f2bf(rows[ni][2]); pv.w = f2bf(rows[ni][3]);
            h4[(nn0 + ni) * 16 + (t & 15)] = pv;
            if ((t & 15) == 0) { as_[nn0 + ni] = vs[ni]; ad_[nn0 + ni] = vd[ni]; }
        }
    }
    // histogram of this block's edge chunk
    int e0 = blockIdx.x * CHUNK;
    int e1 = min(e0 + CHUNK, EE);
    for (int e = e0 + t; e < e1; e += 256) atomicAdd(&hist[dst[e] >> 8], 1);
    __syncthreads();
    for (int i = t; i < NBKT; i += 256) G[blockIdx.x * NBKT + i] = hist[i];
}

// ---------------- k1: per-bucket scan across chunks; block 0 zeroes pool/cntf ----------------

__global__ __launch_bounds__(256) void k1_scan(const int* __restrict__ G, int* __restrict__ offs,
                                               int* __restrict__ bT, float* __restrict__ pool,
                                               float* __restrict__ cntf, int* __restrict__ rowptr) {
    __shared__ int s[256];
    int t = threadIdx.x, j = blockIdx.x;
    int c0 = t * 4;
    int v0 = (c0 + 0 < NCHK) ? G[(c0 + 0) * NBKT + j] : 0;
    int v1 = (c0 + 1 < NCHK) ? G[(c0 + 1) * NBKT + j] : 0;
    int v2 = (c0 + 2 < NCHK) ? G[(c0 + 2) * NBKT + j] : 0;
    int v3 = (c0 + 3 < NCHK) ? G[(c0 + 3) * NBKT + j] : 0;
    int tsum = v0 + v1 + v2 + v3;
    s[t] = tsum;
    __syncthreads();
#pragma unroll
    for (int off = 1; off < 256; off <<= 1) {
        int u = (t >= off) ? s[t - off] : 0;
        __syncthreads();
        s[t] += u;
        __syncthreads();
    }
    int excl = s[t] - tsum;
    if (c0 + 0 < NCHK) offs[(c0 + 0) * NBKT + j] = excl;
    if (c0 + 1 < NCHK) offs[(c0 + 1) * NBKT + j] = excl + v0;
    if (c0 + 2 < NCHK) offs[(c0 + 2) * NBKT + j] = excl + v0 + v1;
    if (c0 + 3 < NCHK) offs[(c0 + 3) * NBKT + j] = excl + v0 + v1 + v2;
    if (t == 255) bT[j] = s[255];
    if (j == 0) {
        for (int i = t; i < GG * CC; i += 256) pool[i] = 0.f;
        if (t < GG) cntf[t] = 0.f;
        if (t == 0) rowptr[NN] = EE;
    }
}

// ---------------- k2: partition edges into bucket-ordered packed pairs ----------------

__global__ __launch_bounds__(256) void k2_part(const int* __restrict__ src, const int* __restrict__ dst,
                                               const int* __restrict__ offs, const int* __restrict__ bT,
                                               unsigned* __restrict__ pairs) {
    __shared__ int s[256];
    __shared__ int bst[NBKT];
    __shared__ int cur[NBKT];
    int t = threadIdx.x, c = blockIdx.x;
    int v = (t < NBKT) ? bT[t] : 0;
    s[t] = v;
    __syncthreads();
#pragma unroll
    for (int off = 1; off < 256; off <<= 1) {
        int u = (t >= off) ? s[t - off] : 0;
        __syncthreads();
        s[t] += u;
        __syncthreads();
    }
    if (t < NBKT) bst[t] = s[t] - v;
    __syncthreads();
    for (int i = t; i < NBKT; i += 256) cur[i] = bst[i] + offs[c * NBKT + i];
    __syncthreads();
    int e0 = c * CHUNK, e1 = min(e0 + CHUNK, EE);
    for (int e = e0 + t; e < e1; e += 256) {
        int d = dst[e];
        int pos = atomicAdd(&cur[d >> 8], 1);
        pairs[pos] = (unsigned)src[e] | ((unsigned)(d & 255) << 16);  // src<2^16, dlocal<2^8
    }
}

// ---------------- k3: per-bucket counting sort -> col + rowptr ----------------

__global__ __launch_bounds__(256) void k3_sort(const unsigned* __restrict__ pairs, const int* __restrict__ bT,
                                               int* __restrict__ col, int* __restrict__ rowptr) {
    __shared__ unsigned pL[CAP];
    __shared__ int hist[256];
    __shared__ int sc[256];
    int t = threadIdx.x, j = blockIdx.x;
    int v = (t < NBKT) ? bT[t] : 0;
    hist[t] = v;
    __syncthreads();
#pragma unroll
    for (int off = 1; off < 256; off <<= 1) {
        int u = (t >= off) ? hist[t - off] : 0;
        __syncthreads();
        hist[t] += u;
        __syncthreads();
    }
    if (t == j) { sc[0] = hist[t] - v; sc[1] = v; }
    __syncthreads();
    int start = sc[0];
    int cnt = sc[1];
    if (cnt > CAP) cnt = CAP;
    int nb = j * 256;
    int nodeCnt = min(256, NN - nb);
    __syncthreads();
    hist[t] = 0;
    __syncthreads();
    for (int i = t; i < cnt; i += 256) {
        unsigned p = pairs[start + i];
        pL[i] = p;
        atomicAdd(&hist[p >> 16], 1);
    }
    __syncthreads();
    int c2 = hist[t];
    sc[t] = c2;
    __syncthreads();
#pragma unroll
    for (int off = 1; off < 256; off <<= 1) {
        int u = (t >= off) ? sc[t - off] : 0;
        __syncthreads();
        sc[t] += u;
        __syncthreads();
    }
    int excl = sc[t] - c2;
    if (t < nodeCnt) rowptr[nb + t] = start + excl;
    hist[t] = excl;
    __syncthreads();
    for (int i = t; i < cnt; i += 256) {
        unsigned p = pL[i];
        int pos = atomicAdd(&hist[p >> 16], 1);
        col[start + pos] = (int)(p & 0xFFFFu);
    }
}

// ---------------- tiled h = x @ W (64->64); bf16 in, bf16 out ----------------

__global__ __launch_bounds__(256) void k_mm64t(const unsigned short* __restrict__ xin,
                                               const float* __restrict__ W,
                                               const float* __restrict__ avs, const float* __restrict__ avd,
                                               unsigned short* __restrict__ h, float* __restrict__ as_,
                                               float* __restrict__ ad_) {
    __shared__ float xT[64 * 68];
    __shared__ float Wl[64 * 64];
    __shared__ float avl[64], adl[64];
    int t = threadIdx.x;
    int nbase = blockIdx.x * 64;
    for (int idx = t; idx < 64 * 64; idx += 256) Wl[idx] = W[idx];
    if (t < 64) { avl[t] = avs[t]; adl[t] = avd[t]; }
    for (int idx = t; idx < 64 * 64; idx += 256) {
        int n = idx / 64, k = idx - n * 64;
        int gn = nbase + n;
        if (gn >= NN) gn = NN - 1;
        xT[k * 68 + n] = bf2f(xin[gn * 64 + k]);
    }
    __syncthreads();
    int f0 = (t & 15) * 4;
    int n0 = (t >> 4) * 4;
    float a00=0,a01=0,a02=0,a03=0, a10=0,a11=0,a12=0,a13=0;
    float a20=0,a21=0,a22=0,a23=0, a30=0,a31=0,a32=0,a33=0;
#pragma unroll 4
    for (int k = 0; k < 64; k++) {
        float4 xv = *(const float4*)&xT[k * 68 + n0];
        float4 wv = *(const float4*)&Wl[k * 64 + f0];
        a00 += xv.x * wv.x; a01 += xv.x * wv.y; a02 += xv.x * wv.z; a03 += xv.x * wv.w;
        a10 += xv.y * wv.x; a11 += xv.y * wv.y; a12 += xv.y * wv.z; a13 += xv.y * wv.w;
        a20 += xv.z * wv.x; a21 += xv.z * wv.y; a22 += xv.z * wv.z; a23 += xv.z * wv.w;
        a30 += xv.w * wv.x; a31 += xv.w * wv.y; a32 += xv.w * wv.z; a33 += xv.w * wv.w;
    }
    float4 av = *(const float4*)&avl[f0];
    float4 dv = *(const float4*)&adl[f0];
    float vs[4], vd[4];
    vs[0] = a00*av.x + a01*av.y + a02*av.z + a03*av.w;
    vs[1] = a10*av.x + a11*av.y + a12*av.z + a13*av.w;
    vs[2] = a20*av.x + a21*av.y + a22*av.z + a23*av.w;
    vs[3] = a30*av.x + a31*av.y + a32*av.z + a33*av.w;
    vd[0] = a00*dv.x + a01*dv.y + a02*dv.z + a03*dv.w;
    vd[1] = a10*dv.x + a11*dv.y + a12*dv.z + a13*dv.w;
    vd[2] = a20*dv.x + a21*dv.y + a22*dv.z + a23*dv.w;
    vd[3] = a30*dv.x + a31*dv.y + a32*dv.z + a33*dv.w;
#pragma unroll
    for (int o = 1; o < 16; o <<= 1) {
#pragma unroll
        for (int ni = 0; ni < 4; ni++) {
            vs[ni] += __shfl_xor(vs[ni], o);
            vd[ni] += __shfl_xor(vd[ni], o);
        }
    }
    ushort4* h4 = (ushort4*)h;
    int nn0 = nbase + n0;
    float rows[4][4] = {{a00,a01,a02,a03},{a10,a11,a12,a13},{a20,a21,a22,a23},{a30,a31,a32,a33}};
#pragma unroll
    for (int ni = 0; ni < 4; ni++) {
        if (nn0 + ni < NN) {
            ushort4 pv;
            pv.x = f2bf(rows[ni][0]); pv.y = f2bf(rows[ni][1]);
            pv.z = f2bf(rows[ni][2]); pv.w = f2bf(rows[ni][3]);
            h4[(nn0 + ni) * 16 + (t & 15)] = pv;
            if ((t & 15) == 0) { as_[nn0 + ni] = vs[ni]; ad_[nn0 + ni] = vd[ni]; }
        }
    }
}

// ---------------- GAT aggregation, 64 features ----------------
// FUSE=false (layer 1): write relu(acc+bias) as bf16 row.
// FUSE=true  (layer 2): in-register h3 = relu(acc+b2) @ W3 (+ layer-3 alpha scalars);
//   hB is never materialized. as3/ad3 are SEPARATE arrays (writing as_ would race with gathers).

template <bool FUSE>
__global__ __launch_bounds__(256) void k_agg64(const unsigned short* __restrict__ h,
                                               const int* __restrict__ rowptr,
                                               const int* __restrict__ col, const float* __restrict__ as_,
                                               const float* __restrict__ ad_, const float* __restrict__ bias,
                                               unsigned short* __restrict__ out16,
                                               const float* __restrict__ W3, const float* __restrict__ a3s,
                                               const float* __restrict__ a3d,
                                               float* __restrict__ as3, float* __restrict__ ad3) {
    __shared__ uint2 ws[4][64];
    __shared__ float W3p[64 * 10];  // pad 8->10: 2-way conflicts only (free per m136)
    if constexpr (FUSE) {
        for (int idx = threadIdx.x; idx < 512; idx += 256)
            W3p[(idx >> 3) * 10 + (idx & 7)] = W3[idx];
    }
    int wid = threadIdx.x >> 6;
    int node = blockIdx.x * 4 + wid;   // NN = 12500*4: every wave valid
    int lane = threadIdx.x & 63;
    int rp0 = rowptr[node];
    int deg = rowptr[node + 1] - rp0;
    float adn = ad_[node];
    float zself = lrelu(as_[node] + adn);
    const ushort4* hb = (const ushort4*)h;
    int f = lane & 15, eg = lane >> 4;
    float4 acc = make_float4(0.f, 0.f, 0.f, 0.f);
    if (deg <= 64) {
        int s = 0;
        float z = -1e30f;
        if (lane < deg) {
            s = col[rp0 + lane];
            z = lrelu(as_[s] + adn);
        }
        float M = z;
#pragma unroll
        for (int o = 32; o; o >>= 1) M = fmaxf(M, __shfl_xor(M, o));
        M = fmaxf(M, zself);
        float ex = (lane < deg) ? __expf(z - M) : 0.f;
        float exs = __expf(zself - M);
        float sum = ex;
#pragma unroll
        for (int o = 32; o; o >>= 1) sum += __shfl_xor(sum, o);
        float inv = 1.f / (sum + exs);
        float wl = ex * inv;   // 0 beyond deg
        ws[wid][lane] = make_uint2(__float_as_uint(wl), (unsigned)s);
        __syncthreads();       // one barrier (both paths); also fences W3p load
        const uint4* wsp = (const uint4*)&ws[wid][0];
        for (int base = 0; base < deg; base += 8) {
            uint4 p = wsp[(base >> 1) + eg];
            float wa = __uint_as_float(p.x);
            float wb = __uint_as_float(p.z);
            ushort4 ha = hb[p.y * 16 + f];
            ushort4 hc = hb[p.w * 16 + f];
            acc.x += wa * bf2f(ha.x) + wb * bf2f(hc.x);
            acc.y += wa * bf2f(ha.y) + wb * bf2f(hc.y);
            acc.z += wa * bf2f(ha.z) + wb * bf2f(hc.z);
            acc.w += wa * bf2f(ha.w) + wb * bf2f(hc.w);
        }
        if (eg == 0) {
            float w0 = exs * inv;
            ushort4 hv = hb[node * 16 + f];
            acc.x += w0 * bf2f(hv.x);
            acc.y += w0 * bf2f(hv.y);
            acc.z += w0 * bf2f(hv.z);
            acc.w += w0 * bf2f(hv.w);
        }
    } else {
        __syncthreads();       // match barrier count
        float m = -1e30f, l = 0.f;
        for (int i = lane; i < deg; i += 64) {
            float z = lrelu(as_[col[rp0 + i]] + adn);
            float mn = fmaxf(m, z);
            l = l * __expf(m - mn) + __expf(z - mn);
            m = mn;
        }
        if (lane == 0) {
            float mn = fmaxf(m, zself);
            l = l * __expf(m - mn) + __expf(zself - mn);
            m = mn;
        }
#pragma unroll
        for (int o = 32; o; o >>= 1) {
            float mo = __shfl_xor(m, o), lo = __shfl_xor(l, o);
            float mn = fmaxf(m, mo);
            l = l * __expf(m - mn) + lo * __expf(mo - mn);
            m = mn;
        }
        float Em = m;
        float inv = 1.f / l;
        for (int base = 0; base < deg; base += 4) {
            int i = base + eg;
            if (i < deg) {
                int sv = col[rp0 + i];
                float al = __expf(lrelu(as_[sv] + adn) - Em) * inv;
                ushort4 hv = hb[sv * 16 + f];
                acc.x += al * bf2f(hv.x);
                acc.y += al * bf2f(hv.y);
                acc.z += al * bf2f(hv.z);
                acc.w += al * bf2f(hv.w);
            }
        }
        if (eg == 0) {
            float al = __expf(zself - Em) * inv;
            ushort4 hv = hb[node * 16 + f];
            acc.x += al * bf2f(hv.x);
            acc.y += al * bf2f(hv.y);
            acc.z += al * bf2f(hv.z);
            acc.w += al * bf2f(hv.w);
        }
    }
#pragma unroll
    for (int o = 16; o <= 32; o <<= 1) {    // after this, ALL lanes hold the reduced row
        acc.x += __shfl_xor(acc.x, o);
        acc.y += __shfl_xor(acc.y, o);
        acc.z += __shfl_xor(acc.z, o);
        acc.w += __shfl_xor(acc.w, o);
    }
    float4 bv = ((const float4*)bias)[f];
    float r0 = fmaxf(acc.x + bv.x, 0.f);
    float r1 = fmaxf(acc.y + bv.y, 0.f);
    float r2 = fmaxf(acc.z + bv.z, 0.f);
    float r3 = fmaxf(acc.w + bv.w, 0.f);
    if constexpr (!FUSE) {
        if (eg == 0) {
            ushort4 pv;
            pv.x = f2bf(r0); pv.y = f2bf(r1); pv.z = f2bf(r2); pv.w = f2bf(r3);
            ((ushort4*)out16)[node * 16 + f] = pv;
        }
    } else {
        // h3[j] = sum_k row2[k] * W3[k][j]; eg owns outputs (2eg, 2eg+1); lane f owns k = 4f..4f+3
        int j0 = eg * 2;
        int kb = f * 4;
        float p0 = 0.f, p1 = 0.f;
#pragma unroll
        for (int i = 0; i < 4; i++) {
            float2 w = *(const float2*)&W3p[(kb + i) * 10 + j0];
            float rv = (i == 0) ? r0 : (i == 1) ? r1 : (i == 2) ? r2 : r3;
            p0 += rv * w.x;
            p1 += rv * w.y;
        }
#pragma unroll
        for (int o = 1; o < 16; o <<= 1) {   // reduce over f (within 16-lane group)
            p0 += __shfl_xor(p0, o);
            p1 += __shfl_xor(p1, o);
        }
        float vs = p0 * a3s[j0] + p1 * a3s[j0 + 1];
        float vd = p0 * a3d[j0] + p1 * a3d[j0 + 1];
        vs += __shfl_xor(vs, 16); vs += __shfl_xor(vs, 32);
        vd += __shfl_xor(vd, 16); vd += __shfl_xor(vd, 32);
        if (lane == 0) { as3[node] = vs; ad3[node] = vd; }
        if (f == 0) {
            ushort2 pv;
            pv.x = f2bf(p0); pv.y = f2bf(p1);
            ((ushort2*)out16)[node * 4 + eg] = pv;
        }
    }
}

// ---------------- layer-3 aggregation fused with mean-pool + sigmoid ----------------

__global__ __launch_bounds__(256) void k_agg8pool(const unsigned short* __restrict__ h,
                                                  const int* __restrict__ rowptr,
                                                  const int* __restrict__ col, const float* __restrict__ as_,
                                                  const float* __restrict__ ad_, const float* __restrict__ bias,
                                                  const int* __restrict__ batch, float* __restrict__ pool,
                                                  float* __restrict__ cntf, float* __restrict__ out) {
    __shared__ uint2 ws[4][64];
    __shared__ float plB[GG * CC];
    __shared__ float plC[GG];
    __shared__ int lastFlag;
    int t = threadIdx.x;
    for (int i = t; i < GG * CC; i += 256) plB[i] = 0.f;
    if (t < GG) plC[t] = 0.f;     // fenced by the mid-kernel __syncthreads below
    int wid = t >> 6;
    int node = blockIdx.x * 4 + wid;
    int lane = t & 63;
    int rp0 = rowptr[node];
    int deg = rowptr[node + 1] - rp0;
    float adn = ad_[node];
    float zself = lrelu(as_[node] + adn);
    const ushort2* h2v = (const ushort2*)h;
    int f = lane & 3, eg = lane >> 2;
    float2 acc = make_float2(0.f, 0.f);
    if (deg <= 64) {
        int s = 0;
        float z = -1e30f;
        if (lane < deg) {
            s = col[rp0 + lane];
            z = lrelu(as_[s] + adn);
        }
        float M = z;
#pragma unroll
        for (int o = 32; o; o >>= 1) M = fmaxf(M, __shfl_xor(M, o));
        M = fmaxf(M, zself);
        float ex = (lane < deg) ? __expf(z - M) : 0.f;
        float exs = __expf(zself - M);
        float sum = ex;
#pragma unroll
        for (int o = 32; o; o >>= 1) sum += __shfl_xor(sum, o);
        float inv = 1.f / (sum + exs);
        float wl = ex * inv;
        ws[wid][lane] = make_uint2(__float_as_uint(wl), (unsigned)s);
        __syncthreads();
        const uint4* wsp = (const uint4*)&ws[wid][0];
        for (int base = 0; base < deg; base += 32) {
            uint4 p = wsp[(base >> 1) + eg];
            float wa = __uint_as_float(p.x);
            float wb = __uint_as_float(p.z);
            ushort2 ha = h2v[p.y * 4 + f];
            ushort2 hc = h2v[p.w * 4 + f];
            acc.x += wa * bf2f(ha.x) + wb * bf2f(hc.x);
            acc.y += wa * bf2f(ha.y) + wb * bf2f(hc.y);
        }
        if (eg == 0) {
            float w0 = exs * inv;
            ushort2 hv = h2v[node * 4 + f];
            acc.x += w0 * bf2f(hv.x);
            acc.y += w0 * bf2f(hv.y);
        }
    } else {
        __syncthreads();
        float m = -1e30f, l = 0.f;
        for (int i = lane; i < deg; i += 64) {
            float z = lrelu(as_[col[rp0 + i]] + adn);
            float mn = fmaxf(m, z);
            l = l * __expf(m - mn) + __expf(z - mn);
            m = mn;
        }
        if (lane == 0) {
            float mn = fmaxf(m, zself);
            l = l * __expf(m - mn) + __expf(zself - mn);
            m = mn;
        }
#pragma unroll
        for (int o = 32; o; o >>= 1) {
            float mo = __shfl_xor(m, o), lo = __shfl_xor(l, o);
            float mn = fmaxf(m, mo);
            l = l * __expf(m - mn) + lo * __expf(mo - mn);
            m = mn;
        }
        float Em = m;
        float inv = 1.f / l;
        for (int base = 0; base < deg; base += 16) {
            int i = base + eg;
            if (i < deg) {
                int sv = col[rp0 + i];
                float al = __expf(lrelu(as_[sv] + adn) - Em) * inv;
                ushort2 hv = h2v[sv * 4 + f];
                acc.x += al * bf2f(hv.x);
                acc.y += al * bf2f(hv.y);
            }
        }
        if (eg == 0) {
            float al = __expf(zself - Em) * inv;
            ushort2 hv = h2v[node * 4 + f];
            acc.x += al * bf2f(hv.x);
            acc.y += al * bf2f(hv.y);
        }
    }
#pragma unroll
    for (int o = 4; o <= 32; o <<= 1) {
        acc.x += __shfl_xor(acc.x, o);
        acc.y += __shfl_xor(acc.y, o);
    }
    // pool accumulate (relu(out3) into per-block LDS pool)
    {
        float2 bvv = ((const float2*)bias)[f];
        float o0 = fmaxf(acc.x + bvv.x, 0.f);
        float o1 = fmaxf(acc.y + bvv.y, 0.f);
        if (eg == 0) {
            int g = batch[node];
            atomicAdd(&plB[g * CC + 2 * f], o0);
            atomicAdd(&plB[g * CC + 2 * f + 1], o1);
            if (f == 0) atomicAdd(&plC[g], 1.0f);
        }
    }
    __syncthreads();
    for (int i = t; i < GG * CC + GG; i += 256) {
        if (i < GG * CC) {
            float v = plB[i];
            if (v != 0.f) atomicAdd(&pool[i], v);
        } else {
            float v = plC[i - GG * CC];
            if (v != 0.f) atomicAdd(&cntf[i - GG * CC], v);
        }
    }
    __syncthreads();
    if (t == 0) {
        __threadfence();
        unsigned r = __hip_atomic_fetch_add(&g_done, 1u, __ATOMIC_ACQ_REL, __HIP_MEMORY_SCOPE_AGENT);
        lastFlag = (r == (unsigned)(NB4G - 1));
    }
    __syncthreads();
    if (lastFlag) {
        __threadfence();
        for (int i = t; i < GG * CC; i += 256) {
            int g = i >> 3;
            float c = __hip_atomic_load(&cntf[g], __ATOMIC_RELAXED, __HIP_MEMORY_SCOPE_AGENT);
            float p = __hip_atomic_load(&pool[i], __ATOMIC_RELAXED, __HIP_MEMORY_SCOPE_AGENT);
            float v = p / fmaxf(c, 1.0f);
            out[i] = 1.0f / (1.0f + __expf(-v));
        }
        if (t == 0)
            __hip_atomic_store(&g_done, 0u, __ATOMIC_RELAXED, __HIP_MEMORY_SCOPE_AGENT);
    }
}

// ---------------- launch ----------------

extern "C" void kernel_launch(void* const* d_in, const int* in_sizes, int n_in,
                              void* d_out, int out_size, void* d_ws, size_t ws_size,
                              hipStream_t stream) {
    const float* x   = (const float*)d_in[0];
    const int*   ei  = (const int*)d_in[1];
    const int*   bat = (const int*)d_in[3];
    const float* W1  = (const float*)d_in[4];
    const float* a1s = (const float*)d_in[5];
    const float* a1d = (const float*)d_in[6];
    const float* b1  = (const float*)d_in[7];
    const float* W2  = (const float*)d_in[8];
    const float* a2s = (const float*)d_in[9];
    const float* a2d = (const float*)d_in[10];
    const float* b2  = (const float*)d_in[11];
    const float* W3  = (const float*)d_in[12];
    const float* a3s = (const float*)d_in[13];
    const float* a3d = (const float*)d_in[14];
    const float* b3  = (const float*)d_in[15];
    float* out = (float*)d_out;

    // workspace carve-up (all bf16 intermediates; hB-L2 and h3b eliminated)
    float* fb = (float*)d_ws;
    unsigned short* hA16 = (unsigned short*)fb;              // N*64 bf16 (N*32 floats)
    unsigned short* hB16 = (unsigned short*)(fb + NN * 32);  // N*64 bf16
    unsigned short* h316 = (unsigned short*)(fb + NN * 64);  // N*8 bf16 (N*4 floats)
    float* as_  = fb + NN * 64 + NN * 4;                     // N
    float* ad_  = as_ + NN;                                  // N
    float* as3  = ad_ + NN;                                  // N (layer-3 alphas: separate, no race)
    float* ad3  = as3 + NN;                                  // N
    int* rowptr = (int*)(ad3 + NN);                          // N+1
    int* col    = rowptr + NN + 1;                           // E
    int* G      = col + EE;                                  // NCHK*NBKT
    int* offs   = G + NCHK * NBKT;                           // NCHK*NBKT
    int* bT     = offs + NCHK * NBKT;                        // 256 (padded)
    unsigned* pairs = (unsigned*)(bT + 256);                 // E
    float* pool = (float*)(pairs + EE);                      // G*C
    float* cntf = pool + GG * CC;                            // G

    const int NB64 = (NN + 63) / 64;     // 782 (= NCHK)

    const int* srcE = ei;
    const int* dstE = ei + EE;

    k0_mm11_hist<<<NB64, 256, 0, stream>>>(x, W1, a1s, a1d, hA16, as_, ad_, dstE, G);
    k1_scan<<<NBKT, 256, 0, stream>>>(G, offs, bT, pool, cntf, rowptr);
    k2_part<<<NCHK, 256, 0, stream>>>(srcE, dstE, offs, bT, pairs);
    k3_sort<<<NBKT, 256, 0, stream>>>(pairs, bT, col, rowptr);

    k_agg64<false><<<NB4G, 256, 0, stream>>>(hA16, rowptr, col, as_, ad_, b1, hB16,
                                             nullptr, nullptr, nullptr, nullptr, nullptr);
    k_mm64t<<<NB64, 256, 0, stream>>>(hB16, W2, a2s, a2d, hA16, as_, ad_);
    k_agg64<true><<<NB4G, 256, 0, stream>>>(hA16, rowptr, col, as_, ad_, b2, h316,
                                            W3, a3s, a3d, as3, ad3);
    k_agg8pool<<<NB4G, 256, 0, stream>>>(h316, rowptr, col, as3, ad3, b3, bat, pool, cntf, out);
}

// Round 12
// 271.263 us; speedup vs baseline: 2.4025x; 2.4025x over previous
//
#include <hip/hip_runtime.h>

#define NN 50000
#define EE 800000
#define GG 64
#define CC 8

#define NBKT 196      // ceil(50000/256) node buckets of 256
#define NCHK 782      // edge chunks = grid of k0 (1024 edges each)
#define CHUNK 1024
#define CAP 8192      // max edges per bucket (mean 4082)
#define NB4G 12500    // agg grids: NN/4

// done-ticket for fused pool+sigmoid (196-block grid ONLY — R11 lesson: never on 12500 blocks)
__device__ unsigned g_done = 0;

__device__ __forceinline__ float lrelu(float z) { return fmaxf(z, 0.2f * z); }
__device__ __forceinline__ unsigned short f2bf(float v) {
    unsigned u = __float_as_uint(v);
    return (unsigned short)((u + 0x7FFFu + ((u >> 16) & 1u)) >> 16);  // RNE
}
__device__ __forceinline__ float bf2f(unsigned short b) {
    return __uint_as_float(((unsigned)b) << 16);
}

// ---------------- k0: layer-1 matmul (CSR-independent) fused with edge histogram ----------------

__global__ __launch_bounds__(256) void k0_mm11_hist(const float* __restrict__ x, const float* __restrict__ W,
                                                    const float* __restrict__ avs, const float* __restrict__ avd,
                                                    unsigned short* __restrict__ h, float* __restrict__ as_,
                                                    float* __restrict__ ad_, const int* __restrict__ dst,
                                                    int* __restrict__ G) {
    __shared__ float xT[11 * 68];
    __shared__ float Wl[11 * 64];
    __shared__ float avl[64], adl[64];
    __shared__ int hist[NBKT];
    int t = threadIdx.x;
    int nbase = blockIdx.x * 64;
    for (int idx = t; idx < 11 * 64; idx += 256) Wl[idx] = W[idx];
    if (t < 64) { avl[t] = avs[t]; adl[t] = avd[t]; }
    for (int idx = t; idx < 64 * 11; idx += 256) {
        int n = idx / 11, k = idx - n * 11;
        int gn = nbase + n;
        if (gn >= NN) gn = NN - 1;
        xT[k * 68 + n] = x[gn * 11 + k];
    }
    for (int i = t; i < NBKT; i += 256) hist[i] = 0;
    __syncthreads();
    int f0 = (t & 15) * 4;
    int n0 = (t >> 4) * 4;
    float a00=0,a01=0,a02=0,a03=0, a10=0,a11=0,a12=0,a13=0;
    float a20=0,a21=0,a22=0,a23=0, a30=0,a31=0,a32=0,a33=0;
#pragma unroll
    for (int k = 0; k < 11; k++) {
        float4 xv = *(const float4*)&xT[k * 68 + n0];
        float4 wv = *(const float4*)&Wl[k * 64 + f0];
        a00 += xv.x * wv.x; a01 += xv.x * wv.y; a02 += xv.x * wv.z; a03 += xv.x * wv.w;
        a10 += xv.y * wv.x; a11 += xv.y * wv.y; a12 += xv.y * wv.z; a13 += xv.y * wv.w;
        a20 += xv.z * wv.x; a21 += xv.z * wv.y; a22 += xv.z * wv.z; a23 += xv.z * wv.w;
        a30 += xv.w * wv.x; a31 += xv.w * wv.y; a32 += xv.w * wv.z; a33 += xv.w * wv.w;
    }
    float4 av = *(const float4*)&avl[f0];
    float4 dv = *(const float4*)&adl[f0];
    float vs[4], vd[4];
    vs[0] = a00*av.x + a01*av.y + a02*av.z + a03*av.w;
    vs[1] = a10*av.x + a11*av.y + a12*av.z + a13*av.w;
    vs[2] = a20*av.x + a21*av.y + a22*av.z + a23*av.w;
    vs[3] = a30*av.x + a31*av.y + a32*av.z + a33*av.w;
    vd[0] = a00*dv.x + a01*dv.y + a02*dv.z + a03*dv.w;
    vd[1] = a10*dv.x + a11*dv.y + a12*dv.z + a13*dv.w;
    vd[2] = a20*dv.x + a21*dv.y + a22*dv.z + a23*dv.w;
    vd[3] = a30*dv.x + a31*dv.y + a32*dv.z + a33*dv.w;
#pragma unroll
    for (int o = 1; o < 16; o <<= 1) {
#pragma unroll
        for (int ni = 0; ni < 4; ni++) {
            vs[ni] += __shfl_xor(vs[ni], o);
            vd[ni] += __shfl_xor(vd[ni], o);
        }
    }
    ushort4* h4 = (ushort4*)h;
    int nn0 = nbase + n0;
    float rows[4][4] = {{a00,a01,a02,a03},{a10,a11,a12,a13},{a20,a21,a22,a23},{a30,a31,a32,a33}};
#pragma unroll
    for (int ni = 0; ni < 4; ni++) {
        if (nn0 + ni < NN) {
            ushort4 pv;
            pv.x = f2bf(rows[ni][0]); pv.y = f2bf(rows[ni][1]);
            pv.z = f2bf(rows[ni][2]); pv.w = f2bf(rows[ni][3]);
            h4[(nn0 + ni) * 16 + (t & 15)] = pv;
            if ((t & 15) == 0) { as_[nn0 + ni] = vs[ni]; ad_[nn0 + ni] = vd[ni]; }
        }
    }
    // histogram of this block's edge chunk
    int e0 = blockIdx.x * CHUNK;
    int e1 = min(e0 + CHUNK, EE);
    for (int e = e0 + t; e < e1; e += 256) atomicAdd(&hist[dst[e] >> 8], 1);
    __syncthreads();
    for (int i = t; i < NBKT; i += 256) G[blockIdx.x * NBKT + i] = hist[i];
}

// ---------------- k1: per-bucket scan across chunks; block 0 zeroes pool/cntf ----------------

__global__ __launch_bounds__(256) void k1_scan(const int* __restrict__ G, int* __restrict__ offs,
                                               int* __restrict__ bT, float* __restrict__ pool,
                                               float* __restrict__ cntf, int* __restrict__ rowptr) {
    __shared__ int s[256];
    int t = threadIdx.x, j = blockIdx.x;
    int c0 = t * 4;
    int v0 = (c0 + 0 < NCHK) ? G[(c0 + 0) * NBKT + j] : 0;
    int v1 = (c0 + 1 < NCHK) ? G[(c0 + 1) * NBKT + j] : 0;
    int v2 = (c0 + 2 < NCHK) ? G[(c0 + 2) * NBKT + j] : 0;
    int v3 = (c0 + 3 < NCHK) ? G[(c0 + 3) * NBKT + j] : 0;
    int tsum = v0 + v1 + v2 + v3;
    s[t] = tsum;
    __syncthreads();
#pragma unroll
    for (int off = 1; off < 256; off <<= 1) {
        int u = (t >= off) ? s[t - off] : 0;
        __syncthreads();
        s[t] += u;
        __syncthreads();
    }
    int excl = s[t] - tsum;
    if (c0 + 0 < NCHK) offs[(c0 + 0) * NBKT + j] = excl;
    if (c0 + 1 < NCHK) offs[(c0 + 1) * NBKT + j] = excl + v0;
    if (c0 + 2 < NCHK) offs[(c0 + 2) * NBKT + j] = excl + v0 + v1;
    if (c0 + 3 < NCHK) offs[(c0 + 3) * NBKT + j] = excl + v0 + v1 + v2;
    if (t == 255) bT[j] = s[255];
    if (j == 0) {
        for (int i = t; i < GG * CC; i += 256) pool[i] = 0.f;
        if (t < GG) cntf[t] = 0.f;
        if (t == 0) rowptr[NN] = EE;
    }
}

// ---------------- k2: partition edges into bucket-ordered packed pairs ----------------

__global__ __launch_bounds__(256) void k2_part(const int* __restrict__ src, const int* __restrict__ dst,
                                               const int* __restrict__ offs, const int* __restrict__ bT,
                                               unsigned* __restrict__ pairs) {
    __shared__ int s[256];
    __shared__ int bst[NBKT];
    __shared__ int cur[NBKT];
    int t = threadIdx.x, c = blockIdx.x;
    int v = (t < NBKT) ? bT[t] : 0;
    s[t] = v;
    __syncthreads();
#pragma unroll
    for (int off = 1; off < 256; off <<= 1) {
        int u = (t >= off) ? s[t - off] : 0;
        __syncthreads();
        s[t] += u;
        __syncthreads();
    }
    if (t < NBKT) bst[t] = s[t] - v;
    __syncthreads();
    for (int i = t; i < NBKT; i += 256) cur[i] = bst[i] + offs[c * NBKT + i];
    __syncthreads();
    int e0 = c * CHUNK, e1 = min(e0 + CHUNK, EE);
    for (int e = e0 + t; e < e1; e += 256) {
        int d = dst[e];
        int pos = atomicAdd(&cur[d >> 8], 1);
        pairs[pos] = (unsigned)src[e] | ((unsigned)(d & 255) << 16);  // src<2^16, dlocal<2^8
    }
}

// ---------------- k3: per-bucket counting sort -> col + rowptr ----------------

__global__ __launch_bounds__(256) void k3_sort(const unsigned* __restrict__ pairs, const int* __restrict__ bT,
                                               int* __restrict__ col, int* __restrict__ rowptr) {
    __shared__ unsigned pL[CAP];
    __shared__ int hist[256];
    __shared__ int sc[256];
    int t = threadIdx.x, j = blockIdx.x;
    int v = (t < NBKT) ? bT[t] : 0;
    hist[t] = v;
    __syncthreads();
#pragma unroll
    for (int off = 1; off < 256; off <<= 1) {
        int u = (t >= off) ? hist[t - off] : 0;
        __syncthreads();
        hist[t] += u;
        __syncthreads();
    }
    if (t == j) { sc[0] = hist[t] - v; sc[1] = v; }
    __syncthreads();
    int start = sc[0];
    int cnt = sc[1];
    if (cnt > CAP) cnt = CAP;
    int nb = j * 256;
    int nodeCnt = min(256, NN - nb);
    __syncthreads();
    hist[t] = 0;
    __syncthreads();
    for (int i = t; i < cnt; i += 256) {
        unsigned p = pairs[start + i];
        pL[i] = p;
        atomicAdd(&hist[p >> 16], 1);
    }
    __syncthreads();
    int c2 = hist[t];
    sc[t] = c2;
    __syncthreads();
#pragma unroll
    for (int off = 1; off < 256; off <<= 1) {
        int u = (t >= off) ? sc[t - off] : 0;
        __syncthreads();
        sc[t] += u;
        __syncthreads();
    }
    int excl = sc[t] - c2;
    if (t < nodeCnt) rowptr[nb + t] = start + excl;
    hist[t] = excl;
    __syncthreads();
    for (int i = t; i < cnt; i += 256) {
        unsigned p = pL[i];
        int pos = atomicAdd(&hist[p >> 16], 1);
        col[start + pos] = (int)(p & 0xFFFFu);
    }
}

// ---------------- tiled h = x @ W (64->64); bf16 in, bf16 out ----------------

__global__ __launch_bounds__(256) void k_mm64t(const unsigned short* __restrict__ xin,
                                               const float* __restrict__ W,
                                               const float* __restrict__ avs, const float* __restrict__ avd,
                                               unsigned short* __restrict__ h, float* __restrict__ as_,
                                               float* __restrict__ ad_) {
    __shared__ float xT[64 * 68];
    __shared__ float Wl[64 * 64];
    __shared__ float avl[64], adl[64];
    int t = threadIdx.x;
    int nbase = blockIdx.x * 64;
    for (int idx = t; idx < 64 * 64; idx += 256) Wl[idx] = W[idx];
    if (t < 64) { avl[t] = avs[t]; adl[t] = avd[t]; }
    for (int idx = t; idx < 64 * 64; idx += 256) {
        int n = idx / 64, k = idx - n * 64;
        int gn = nbase + n;
        if (gn >= NN) gn = NN - 1;
        xT[k * 68 + n] = bf2f(xin[gn * 64 + k]);
    }
    __syncthreads();
    int f0 = (t & 15) * 4;
    int n0 = (t >> 4) * 4;
    float a00=0,a01=0,a02=0,a03=0, a10=0,a11=0,a12=0,a13=0;
    float a20=0,a21=0,a22=0,a23=0, a30=0,a31=0,a32=0,a33=0;
#pragma unroll 4
    for (int k = 0; k < 64; k++) {
        float4 xv = *(const float4*)&xT[k * 68 + n0];
        float4 wv = *(const float4*)&Wl[k * 64 + f0];
        a00 += xv.x * wv.x; a01 += xv.x * wv.y; a02 += xv.x * wv.z; a03 += xv.x * wv.w;
        a10 += xv.y * wv.x; a11 += xv.y * wv.y; a12 += xv.y * wv.z; a13 += xv.y * wv.w;
        a20 += xv.z * wv.x; a21 += xv.z * wv.y; a22 += xv.z * wv.z; a23 += xv.z * wv.w;
        a30 += xv.w * wv.x; a31 += xv.w * wv.y; a32 += xv.w * wv.z; a33 += xv.w * wv.w;
    }
    float4 av = *(const float4*)&avl[f0];
    float4 dv = *(const float4*)&adl[f0];
    float vs[4], vd[4];
    vs[0] = a00*av.x + a01*av.y + a02*av.z + a03*av.w;
    vs[1] = a10*av.x + a11*av.y + a12*av.z + a13*av.w;
    vs[2] = a20*av.x + a21*av.y + a22*av.z + a23*av.w;
    vs[3] = a30*av.x + a31*av.y + a32*av.z + a33*av.w;
    vd[0] = a00*dv.x + a01*dv.y + a02*dv.z + a03*dv.w;
    vd[1] = a10*dv.x + a11*dv.y + a12*dv.z + a13*dv.w;
    vd[2] = a20*dv.x + a21*dv.y + a22*dv.z + a23*dv.w;
    vd[3] = a30*dv.x + a31*dv.y + a32*dv.z + a33*dv.w;
#pragma unroll
    for (int o = 1; o < 16; o <<= 1) {
#pragma unroll
        for (int ni = 0; ni < 4; ni++) {
            vs[ni] += __shfl_xor(vs[ni], o);
            vd[ni] += __shfl_xor(vd[ni], o);
        }
    }
    ushort4* h4 = (ushort4*)h;
    int nn0 = nbase + n0;
    float rows[4][4] = {{a00,a01,a02,a03},{a10,a11,a12,a13},{a20,a21,a22,a23},{a30,a31,a32,a33}};
#pragma unroll
    for (int ni = 0; ni < 4; ni++) {
        if (nn0 + ni < NN) {
            ushort4 pv;
            pv.x = f2bf(rows[ni][0]); pv.y = f2bf(rows[ni][1]);
            pv.z = f2bf(rows[ni][2]); pv.w = f2bf(rows[ni][3]);
            h4[(nn0 + ni) * 16 + (t & 15)] = pv;
            if ((t & 15) == 0) { as_[nn0 + ni] = vs[ni]; ad_[nn0 + ni] = vd[ni]; }
        }
    }
}

// ---------------- GAT aggregation, 64 features ----------------
// FUSE=false (layer 1): write relu(acc+bias) as bf16 row.
// FUSE=true  (layer 2): in-register h3 = relu(acc+b2) @ W3 (+ layer-3 alpha scalars);
//   hB-L2 never materialized. as3/ad3 separate arrays (no race with gathers).

template <bool FUSE>
__global__ __launch_bounds__(256) void k_agg64(const unsigned short* __restrict__ h,
                                               const int* __restrict__ rowptr,
                                               const int* __restrict__ col, const float* __restrict__ as_,
                                               const float* __restrict__ ad_, const float* __restrict__ bias,
                                               unsigned short* __restrict__ out16,
                                               const float* __restrict__ W3, const float* __restrict__ a3s,
                                               const float* __restrict__ a3d,
                                               float* __restrict__ as3, float* __restrict__ ad3) {
    __shared__ uint2 ws[4][64];
    __shared__ float W3p[64 * 10];  // pad 8->10: 2-way conflicts only
    if constexpr (FUSE) {
        for (int idx = threadIdx.x; idx < 512; idx += 256)
            W3p[(idx >> 3) * 10 + (idx & 7)] = W3[idx];
    }
    int wid = threadIdx.x >> 6;
    int node = blockIdx.x * 4 + wid;   // NN = 12500*4: every wave valid
    int lane = threadIdx.x & 63;
    int rp0 = rowptr[node];
    int deg = rowptr[node + 1] - rp0;
    float adn = ad_[node];
    float zself = lrelu(as_[node] + adn);
    const ushort4* hb = (const ushort4*)h;
    int f = lane & 15, eg = lane >> 4;
    float4 acc = make_float4(0.f, 0.f, 0.f, 0.f);
    if (deg <= 64) {
        int s = 0;
        float z = -1e30f;
        if (lane < deg) {
            s = col[rp0 + lane];
            z = lrelu(as_[s] + adn);
        }
        float M = z;
#pragma unroll
        for (int o = 32; o; o >>= 1) M = fmaxf(M, __shfl_xor(M, o));
        M = fmaxf(M, zself);
        float ex = (lane < deg) ? __expf(z - M) : 0.f;
        float exs = __expf(zself - M);
        float sum = ex;
#pragma unroll
        for (int o = 32; o; o >>= 1) sum += __shfl_xor(sum, o);
        float inv = 1.f / (sum + exs);
        float wl = ex * inv;   // 0 beyond deg
        ws[wid][lane] = make_uint2(__float_as_uint(wl), (unsigned)s);
        __syncthreads();       // one barrier (both paths); also fences W3p load
        const uint4* wsp = (const uint4*)&ws[wid][0];
        for (int base = 0; base < deg; base += 8) {
            uint4 p = wsp[(base >> 1) + eg];
            float wa = __uint_as_float(p.x);
            float wb = __uint_as_float(p.z);
            ushort4 ha = hb[p.y * 16 + f];
            ushort4 hc = hb[p.w * 16 + f];
            acc.x += wa * bf2f(ha.x) + wb * bf2f(hc.x);
            acc.y += wa * bf2f(ha.y) + wb * bf2f(hc.y);
            acc.z += wa * bf2f(ha.z) + wb * bf2f(hc.z);
            acc.w += wa * bf2f(ha.w) + wb * bf2f(hc.w);
        }
        if (eg == 0) {
            float w0 = exs * inv;
            ushort4 hv = hb[node * 16 + f];
            acc.x += w0 * bf2f(hv.x);
            acc.y += w0 * bf2f(hv.y);
            acc.z += w0 * bf2f(hv.z);
            acc.w += w0 * bf2f(hv.w);
        }
    } else {
        __syncthreads();       // match barrier count
        float m = -1e30f, l = 0.f;
        for (int i = lane; i < deg; i += 64) {
            float z = lrelu(as_[col[rp0 + i]] + adn);
            float mn = fmaxf(m, z);
            l = l * __expf(m - mn) + __expf(z - mn);
            m = mn;
        }
        if (lane == 0) {
            float mn = fmaxf(m, zself);
            l = l * __expf(m - mn) + __expf(zself - mn);
            m = mn;
        }
#pragma unroll
        for (int o = 32; o; o >>= 1) {
            float mo = __shfl_xor(m, o), lo = __shfl_xor(l, o);
            float mn = fmaxf(m, mo);
            l = l * __expf(m - mn) + lo * __expf(mo - mn);
            m = mn;
        }
        float Em = m;
        float inv = 1.f / l;
        for (int base = 0; base < deg; base += 4) {
            int i = base + eg;
            if (i < deg) {
                int sv = col[rp0 + i];
                float al = __expf(lrelu(as_[sv] + adn) - Em) * inv;
                ushort4 hv = hb[sv * 16 + f];
                acc.x += al * bf2f(hv.x);
                acc.y += al * bf2f(hv.y);
                acc.z += al * bf2f(hv.z);
                acc.w += al * bf2f(hv.w);
            }
        }
        if (eg == 0) {
            float al = __expf(zself - Em) * inv;
            ushort4 hv = hb[node * 16 + f];
            acc.x += al * bf2f(hv.x);
            acc.y += al * bf2f(hv.y);
            acc.z += al * bf2f(hv.z);
            acc.w += al * bf2f(hv.w);
        }
    }
#pragma unroll
    for (int o = 16; o <= 32; o <<= 1) {    // after this, ALL lanes hold the reduced row
        acc.x += __shfl_xor(acc.x, o);
        acc.y += __shfl_xor(acc.y, o);
        acc.z += __shfl_xor(acc.z, o);
        acc.w += __shfl_xor(acc.w, o);
    }
    float4 bv = ((const float4*)bias)[f];
    float r0 = fmaxf(acc.x + bv.x, 0.f);
    float r1 = fmaxf(acc.y + bv.y, 0.f);
    float r2 = fmaxf(acc.z + bv.z, 0.f);
    float r3 = fmaxf(acc.w + bv.w, 0.f);
    if constexpr (!FUSE) {
        if (eg == 0) {
            ushort4 pv;
            pv.x = f2bf(r0); pv.y = f2bf(r1); pv.z = f2bf(r2); pv.w = f2bf(r3);
            ((ushort4*)out16)[node * 16 + f] = pv;
        }
    } else {
        // h3[j] = sum_k row2[k] * W3[k][j]; eg owns outputs (2eg, 2eg+1); lane f owns k = 4f..4f+3
        int j0 = eg * 2;
        int kb = f * 4;
        float p0 = 0.f, p1 = 0.f;
#pragma unroll
        for (int i = 0; i < 4; i++) {
            float2 w = *(const float2*)&W3p[(kb + i) * 10 + j0];
            float rv = (i == 0) ? r0 : (i == 1) ? r1 : (i == 2) ? r2 : r3;
            p0 += rv * w.x;
            p1 += rv * w.y;
        }
#pragma unroll
        for (int o = 1; o < 16; o <<= 1) {   // reduce over f (within 16-lane group)
            p0 += __shfl_xor(p0, o);
            p1 += __shfl_xor(p1, o);
        }
        float vs = p0 * a3s[j0] + p1 * a3s[j0 + 1];
        float vd = p0 * a3d[j0] + p1 * a3d[j0 + 1];
        vs += __shfl_xor(vs, 16); vs += __shfl_xor(vs, 32);
        vd += __shfl_xor(vd, 16); vd += __shfl_xor(vd, 32);
        if (lane == 0) { as3[node] = vs; ad3[node] = vd; }
        if (f == 0) {
            ushort2 pv;
            pv.x = f2bf(p0); pv.y = f2bf(p1);
            ((ushort2*)out16)[node * 4 + eg] = pv;
        }
    }
}

// ---------------- layer-3 aggregation (12500 blocks, NO global atomics) ----------------

__global__ __launch_bounds__(256) void k_agg8(const unsigned short* __restrict__ h,
                                              const int* __restrict__ rowptr,
                                              const int* __restrict__ col, const float* __restrict__ as_,
                                              const float* __restrict__ ad_, const float* __restrict__ bias,
                                              float* __restrict__ out) {
    __shared__ uint2 ws[4][64];
    int wid = threadIdx.x >> 6;
    int node = blockIdx.x * 4 + wid;
    int lane = threadIdx.x & 63;
    int rp0 = rowptr[node];
    int deg = rowptr[node + 1] - rp0;
    float adn = ad_[node];
    float zself = lrelu(as_[node] + adn);
    const ushort2* h2v = (const ushort2*)h;
    int f = lane & 3, eg = lane >> 2;
    float2 acc = make_float2(0.f, 0.f);
    if (deg <= 64) {
        int s = 0;
        float z = -1e30f;
        if (lane < deg) {
            s = col[rp0 + lane];
            z = lrelu(as_[s] + adn);
        }
        float M = z;
#pragma unroll
        for (int o = 32; o; o >>= 1) M = fmaxf(M, __shfl_xor(M, o));
        M = fmaxf(M, zself);
        float ex = (lane < deg) ? __expf(z - M) : 0.f;
        float exs = __expf(zself - M);
        float sum = ex;
#pragma unroll
        for (int o = 32; o; o >>= 1) sum += __shfl_xor(sum, o);
        float inv = 1.f / (sum + exs);
        float wl = ex * inv;
        ws[wid][lane] = make_uint2(__float_as_uint(wl), (unsigned)s);
        __syncthreads();
        const uint4* wsp = (const uint4*)&ws[wid][0];
        for (int base = 0; base < deg; base += 32) {
            uint4 p = wsp[(base >> 1) + eg];
            float wa = __uint_as_float(p.x);
            float wb = __uint_as_float(p.z);
            ushort2 ha = h2v[p.y * 4 + f];
            ushort2 hc = h2v[p.w * 4 + f];
            acc.x += wa * bf2f(ha.x) + wb * bf2f(hc.x);
            acc.y += wa * bf2f(ha.y) + wb * bf2f(hc.y);
        }
        if (eg == 0) {
            float w0 = exs * inv;
            ushort2 hv = h2v[node * 4 + f];
            acc.x += w0 * bf2f(hv.x);
            acc.y += w0 * bf2f(hv.y);
        }
    } else {
        __syncthreads();
        float m = -1e30f, l = 0.f;
        for (int i = lane; i < deg; i += 64) {
            float z = lrelu(as_[col[rp0 + i]] + adn);
            float mn = fmaxf(m, z);
            l = l * __expf(m - mn) + __expf(z - mn);
            m = mn;
        }
        if (lane == 0) {
            float mn = fmaxf(m, zself);
            l = l * __expf(m - mn) + __expf(zself - mn);
            m = mn;
        }
#pragma unroll
        for (int o = 32; o; o >>= 1) {
            float mo = __shfl_xor(m, o), lo = __shfl_xor(l, o);
            float mn = fmaxf(m, mo);
            l = l * __expf(m - mn) + lo * __expf(mo - mn);
            m = mn;
        }
        float Em = m;
        float inv = 1.f / l;
        for (int base = 0; base < deg; base += 16) {
            int i = base + eg;
            if (i < deg) {
                int sv = col[rp0 + i];
                float al = __expf(lrelu(as_[sv] + adn) - Em) * inv;
                ushort2 hv = h2v[sv * 4 + f];
                acc.x += al * bf2f(hv.x);
                acc.y += al * bf2f(hv.y);
            }
        }
        if (eg == 0) {
            float al = __expf(zself - Em) * inv;
            ushort2 hv = h2v[node * 4 + f];
            acc.x += al * bf2f(hv.x);
            acc.y += al * bf2f(hv.y);
        }
    }
#pragma unroll
    for (int o = 4; o <= 32; o <<= 1) {
        acc.x += __shfl_xor(acc.x, o);
        acc.y += __shfl_xor(acc.y, o);
    }
    if (eg == 0) {
        float2 bv = ((const float2*)bias)[f];
        float2 o2;
        o2.x = fmaxf(acc.x + bv.x, 0.f);
        o2.y = fmaxf(acc.y + bv.y, 0.f);
        ((float2*)out)[node * 4 + f] = o2;
    }
}

// ---------------- k9: mean-pool + sigmoid (196 blocks, done-ticket; R9/R10-verified) ----------------

__global__ __launch_bounds__(256) void k9_poolfinal(const float* __restrict__ h3, const int* __restrict__ batch,
                                                    float* __restrict__ pool, float* __restrict__ cntf,
                                                    float* __restrict__ out) {
    __shared__ float pl[GG * CC + GG];
    __shared__ int lastFlag;
    int t = threadIdx.x;
    for (int idx = t; idx < GG * CC + GG; idx += 256) pl[idx] = 0.f;
    __syncthreads();
    int node = blockIdx.x * 256 + t;
    if (node < NN) {
        int g = batch[node];
#pragma unroll
        for (int c = 0; c < CC; c++) atomicAdd(&pl[g * CC + c], h3[node * CC + c]);
        atomicAdd(&pl[GG * CC + g], 1.0f);
    }
    __syncthreads();
    for (int idx = t; idx < GG * CC + GG; idx += 256) {
        float v = pl[idx];
        if (idx < GG * CC)
            atomicAdd(&pool[idx], v);
        else
            atomicAdd(&cntf[idx - GG * CC], v);
    }
    __syncthreads();
    if (t == 0) {
        __threadfence();
        unsigned r = __hip_atomic_fetch_add(&g_done, 1u, __ATOMIC_ACQ_REL, __HIP_MEMORY_SCOPE_AGENT);
        lastFlag = (r == (unsigned)(NBKT - 1));
    }
    __syncthreads();
    if (lastFlag) {
        __threadfence();
        for (int i = t; i < GG * CC; i += 256) {
            int g = i >> 3;
            float c = __hip_atomic_load(&cntf[g], __ATOMIC_RELAXED, __HIP_MEMORY_SCOPE_AGENT);
            float p = __hip_atomic_load(&pool[i], __ATOMIC_RELAXED, __HIP_MEMORY_SCOPE_AGENT);
            float v = p / fmaxf(c, 1.0f);
            out[i] = 1.0f / (1.0f + __expf(-v));
        }
        if (t == 0)
            __hip_atomic_store(&g_done, 0u, __ATOMIC_RELAXED, __HIP_MEMORY_SCOPE_AGENT);
    }
}

// ---------------- launch ----------------

extern "C" void kernel_launch(void* const* d_in, const int* in_sizes, int n_in,
                              void* d_out, int out_size, void* d_ws, size_t ws_size,
                              hipStream_t stream) {
    const float* x   = (const float*)d_in[0];
    const int*   ei  = (const int*)d_in[1];
    const int*   bat = (const int*)d_in[3];
    const float* W1  = (const float*)d_in[4];
    const float* a1s = (const float*)d_in[5];
    const float* a1d = (const float*)d_in[6];
    const float* b1  = (const float*)d_in[7];
    const float* W2  = (const float*)d_in[8];
    const float* a2s = (const float*)d_in[9];
    const float* a2d = (const float*)d_in[10];
    const float* b2  = (const float*)d_in[11];
    const float* W3  = (const float*)d_in[12];
    const float* a3s = (const float*)d_in[13];
    const float* a3d = (const float*)d_in[14];
    const float* b3  = (const float*)d_in[15];
    float* out = (float*)d_out;

    // workspace carve-up
    float* fb = (float*)d_ws;
    unsigned short* hA16 = (unsigned short*)fb;              // N*64 bf16 (N*32 floats)
    unsigned short* hB16 = (unsigned short*)(fb + NN * 32);  // N*64 bf16
    unsigned short* h316 = (unsigned short*)(fb + NN * 64);  // N*8 bf16 (N*4 floats)
    float* h3b  = fb + NN * 64 + NN * 4;                     // N*8 f32
    float* as_  = h3b + NN * 8;                              // N
    float* ad_  = as_ + NN;                                  // N
    float* as3  = ad_ + NN;                                  // N
    float* ad3  = as3 + NN;                                  // N
    int* rowptr = (int*)(ad3 + NN);                          // N+1
    int* col    = rowptr + NN + 1;                           // E
    int* G      = col + EE;                                  // NCHK*NBKT
    int* offs   = G + NCHK * NBKT;                           // NCHK*NBKT
    int* bT     = offs + NCHK * NBKT;                        // 256 (padded)
    unsigned* pairs = (unsigned*)(bT + 256);                 // E
    float* pool = (float*)(pairs + EE);                      // G*C
    float* cntf = pool + GG * CC;                            // G

    const int NB64 = (NN + 63) / 64;     // 782 (= NCHK)

    const int* srcE = ei;
    const int* dstE = ei + EE;

    k0_mm11_hist<<<NB64, 256, 0, stream>>>(x, W1, a1s, a1d, hA16, as_, ad_, dstE, G);
    k1_scan<<<NBKT, 256, 0, stream>>>(G, offs, bT, pool, cntf, rowptr);
    k2_part<<<NCHK, 256, 0, stream>>>(srcE, dstE, offs, bT, pairs);
    k3_sort<<<NBKT, 256, 0, stream>>>(pairs, bT, col, rowptr);

    k_agg64<false><<<NB4G, 256, 0, stream>>>(hA16, rowptr, col, as_, ad_, b1, hB16,
                                             nullptr, nullptr, nullptr, nullptr, nullptr);
    k_mm64t<<<NB64, 256, 0, stream>>>(hB16, W2, a2s, a2d, hA16, as_, ad_);
    k_agg64<true><<<NB4G, 256, 0, stream>>>(hA16, rowptr, col, as_, ad_, b2, h316,
                                            W3, a3s, a3d, as3, ad3);
    k_agg8<<<NB4G, 256, 0, stream>>>(h316, rowptr, col, as3, ad3, b3, h3b);
    k9_poolfinal<<<NBKT, 256, 0, stream>>>(h3b, bat, pool, cntf, out);
}

// Round 13
// 270.166 us; speedup vs baseline: 2.4122x; 1.0041x over previous
//
#include <hip/hip_runtime.h>

#define NN 50000
#define EE 800000
#define GG 64
#define CC 8

#define NBKT 196      // ceil(50000/256) node buckets of 256
#define NCHK 782      // edge chunks = grid of k0 (1024 edges each)
#define CHUNK 1024
#define CAP 8192      // max edges per bucket (mean 4082)
#define NB4G 12500    // agg grids: NN/4

// done-ticket for fused pool+sigmoid (196-block grid ONLY — R11 lesson: never on 12500 blocks)
__device__ unsigned g_done = 0;

__device__ __forceinline__ float lrelu(float z) { return fmaxf(z, 0.2f * z); }
__device__ __forceinline__ unsigned short f2bf(float v) {
    unsigned u = __float_as_uint(v);
    return (unsigned short)((u + 0x7FFFu + ((u >> 16) & 1u)) >> 16);  // RNE
}
__device__ __forceinline__ float bf2f(unsigned short b) {
    return __uint_as_float(((unsigned)b) << 16);
}
// unpack 2 bf16 from one dword: 1 VALU op per value
__device__ __forceinline__ float2 bf2x2(unsigned d) {
    float2 r;
    r.x = __uint_as_float(d << 16);
    r.y = __uint_as_float(d & 0xFFFF0000u);
    return r;
}

// ---------------- k0: layer-1 matmul (CSR-independent) fused with edge histogram ----------------

__global__ __launch_bounds__(256) void k0_mm11_hist(const float* __restrict__ x, const float* __restrict__ W,
                                                    const float* __restrict__ avs, const float* __restrict__ avd,
                                                    unsigned short* __restrict__ h, float* __restrict__ as_,
                                                    float* __restrict__ ad_, const int* __restrict__ dst,
                                                    int* __restrict__ G) {
    __shared__ float xT[11 * 68];
    __shared__ float Wl[11 * 64];
    __shared__ float avl[64], adl[64];
    __shared__ int hist[NBKT];
    int t = threadIdx.x;
    int nbase = blockIdx.x * 64;
    for (int idx = t; idx < 11 * 64; idx += 256) Wl[idx] = W[idx];
    if (t < 64) { avl[t] = avs[t]; adl[t] = avd[t]; }
    for (int idx = t; idx < 64 * 11; idx += 256) {
        int n = idx / 11, k = idx - n * 11;
        int gn = nbase + n;
        if (gn >= NN) gn = NN - 1;
        xT[k * 68 + n] = x[gn * 11 + k];
    }
    for (int i = t; i < NBKT; i += 256) hist[i] = 0;
    __syncthreads();
    int f0 = (t & 15) * 4;
    int n0 = (t >> 4) * 4;
    float a00=0,a01=0,a02=0,a03=0, a10=0,a11=0,a12=0,a13=0;
    float a20=0,a21=0,a22=0,a23=0, a30=0,a31=0,a32=0,a33=0;
#pragma unroll
    for (int k = 0; k < 11; k++) {
        float4 xv = *(const float4*)&xT[k * 68 + n0];
        float4 wv = *(const float4*)&Wl[k * 64 + f0];
        a00 += xv.x * wv.x; a01 += xv.x * wv.y; a02 += xv.x * wv.z; a03 += xv.x * wv.w;
        a10 += xv.y * wv.x; a11 += xv.y * wv.y; a12 += xv.y * wv.z; a13 += xv.y * wv.w;
        a20 += xv.z * wv.x; a21 += xv.z * wv.y; a22 += xv.z * wv.z; a23 += xv.z * wv.w;
        a30 += xv.w * wv.x; a31 += xv.w * wv.y; a32 += xv.w * wv.z; a33 += xv.w * wv.w;
    }
    float4 av = *(const float4*)&avl[f0];
    float4 dv = *(const float4*)&adl[f0];
    float vs[4], vd[4];
    vs[0] = a00*av.x + a01*av.y + a02*av.z + a03*av.w;
    vs[1] = a10*av.x + a11*av.y + a12*av.z + a13*av.w;
    vs[2] = a20*av.x + a21*av.y + a22*av.z + a23*av.w;
    vs[3] = a30*av.x + a31*av.y + a32*av.z + a33*av.w;
    vd[0] = a00*dv.x + a01*dv.y + a02*dv.z + a03*dv.w;
    vd[1] = a10*dv.x + a11*dv.y + a12*dv.z + a13*dv.w;
    vd[2] = a20*dv.x + a21*dv.y + a22*dv.z + a23*dv.w;
    vd[3] = a30*dv.x + a31*dv.y + a32*dv.z + a33*dv.w;
#pragma unroll
    for (int o = 1; o < 16; o <<= 1) {
#pragma unroll
        for (int ni = 0; ni < 4; ni++) {
            vs[ni] += __shfl_xor(vs[ni], o);
            vd[ni] += __shfl_xor(vd[ni], o);
        }
    }
    ushort4* h4 = (ushort4*)h;
    int nn0 = nbase + n0;
    float rows[4][4] = {{a00,a01,a02,a03},{a10,a11,a12,a13},{a20,a21,a22,a23},{a30,a31,a32,a33}};
#pragma unroll
    for (int ni = 0; ni < 4; ni++) {
        if (nn0 + ni < NN) {
            ushort4 pv;
            pv.x = f2bf(rows[ni][0]); pv.y = f2bf(rows[ni][1]);
            pv.z = f2bf(rows[ni][2]); pv.w = f2bf(rows[ni][3]);
            h4[(nn0 + ni) * 16 + (t & 15)] = pv;
            if ((t & 15) == 0) { as_[nn0 + ni] = vs[ni]; ad_[nn0 + ni] = vd[ni]; }
        }
    }
    int e0 = blockIdx.x * CHUNK;
    int e1 = min(e0 + CHUNK, EE);
    for (int e = e0 + t; e < e1; e += 256) atomicAdd(&hist[dst[e] >> 8], 1);
    __syncthreads();
    for (int i = t; i < NBKT; i += 256) G[blockIdx.x * NBKT + i] = hist[i];
}

// ---------------- k1: per-bucket scan across chunks; block 0 zeroes pool/cntf ----------------

__global__ __launch_bounds__(256) void k1_scan(const int* __restrict__ G, int* __restrict__ offs,
                                               int* __restrict__ bT, float* __restrict__ pool,
                                               float* __restrict__ cntf, int* __restrict__ rowptr) {
    __shared__ int s[256];
    int t = threadIdx.x, j = blockIdx.x;
    int c0 = t * 4;
    int v0 = (c0 + 0 < NCHK) ? G[(c0 + 0) * NBKT + j] : 0;
    int v1 = (c0 + 1 < NCHK) ? G[(c0 + 1) * NBKT + j] : 0;
    int v2 = (c0 + 2 < NCHK) ? G[(c0 + 2) * NBKT + j] : 0;
    int v3 = (c0 + 3 < NCHK) ? G[(c0 + 3) * NBKT + j] : 0;
    int tsum = v0 + v1 + v2 + v3;
    s[t] = tsum;
    __syncthreads();
#pragma unroll
    for (int off = 1; off < 256; off <<= 1) {
        int u = (t >= off) ? s[t - off] : 0;
        __syncthreads();
        s[t] += u;
        __syncthreads();
    }
    int excl = s[t] - tsum;
    if (c0 + 0 < NCHK) offs[(c0 + 0) * NBKT + j] = excl;
    if (c0 + 1 < NCHK) offs[(c0 + 1) * NBKT + j] = excl + v0;
    if (c0 + 2 < NCHK) offs[(c0 + 2) * NBKT + j] = excl + v0 + v1;
    if (c0 + 3 < NCHK) offs[(c0 + 3) * NBKT + j] = excl + v0 + v1 + v2;
    if (t == 255) bT[j] = s[255];
    if (j == 0) {
        for (int i = t; i < GG * CC; i += 256) pool[i] = 0.f;
        if (t < GG) cntf[t] = 0.f;
        if (t == 0) rowptr[NN] = EE;
    }
}

// ---------------- k2: partition edges into bucket-ordered packed pairs ----------------

__global__ __launch_bounds__(256) void k2_part(const int* __restrict__ src, const int* __restrict__ dst,
                                               const int* __restrict__ offs, const int* __restrict__ bT,
                                               unsigned* __restrict__ pairs) {
    __shared__ int s[256];
    __shared__ int bst[NBKT];
    __shared__ int cur[NBKT];
    int t = threadIdx.x, c = blockIdx.x;
    int v = (t < NBKT) ? bT[t] : 0;
    s[t] = v;
    __syncthreads();
#pragma unroll
    for (int off = 1; off < 256; off <<= 1) {
        int u = (t >= off) ? s[t - off] : 0;
        __syncthreads();
        s[t] += u;
        __syncthreads();
    }
    if (t < NBKT) bst[t] = s[t] - v;
    __syncthreads();
    for (int i = t; i < NBKT; i += 256) cur[i] = bst[i] + offs[c * NBKT + i];
    __syncthreads();
    int e0 = c * CHUNK, e1 = min(e0 + CHUNK, EE);
    for (int e = e0 + t; e < e1; e += 256) {
        int d = dst[e];
        int pos = atomicAdd(&cur[d >> 8], 1);
        pairs[pos] = (unsigned)src[e] | ((unsigned)(d & 255) << 16);  // src<2^16, dlocal<2^8
    }
}

// ---------------- k3: per-bucket counting sort -> col + rowptr ----------------

__global__ __launch_bounds__(256) void k3_sort(const unsigned* __restrict__ pairs, const int* __restrict__ bT,
                                               int* __restrict__ col, int* __restrict__ rowptr) {
    __shared__ unsigned pL[CAP];
    __shared__ int hist[256];
    __shared__ int sc[256];
    int t = threadIdx.x, j = blockIdx.x;
    int v = (t < NBKT) ? bT[t] : 0;
    hist[t] = v;
    __syncthreads();
#pragma unroll
    for (int off = 1; off < 256; off <<= 1) {
        int u = (t >= off) ? hist[t - off] : 0;
        __syncthreads();
        hist[t] += u;
        __syncthreads();
    }
    if (t == j) { sc[0] = hist[t] - v; sc[1] = v; }
    __syncthreads();
    int start = sc[0];
    int cnt = sc[1];
    if (cnt > CAP) cnt = CAP;
    int nb = j * 256;
    int nodeCnt = min(256, NN - nb);
    __syncthreads();
    hist[t] = 0;
    __syncthreads();
    for (int i = t; i < cnt; i += 256) {
        unsigned p = pairs[start + i];
        pL[i] = p;
        atomicAdd(&hist[p >> 16], 1);
    }
    __syncthreads();
    int c2 = hist[t];
    sc[t] = c2;
    __syncthreads();
#pragma unroll
    for (int off = 1; off < 256; off <<= 1) {
        int u = (t >= off) ? sc[t - off] : 0;
        __syncthreads();
        sc[t] += u;
        __syncthreads();
    }
    int excl = sc[t] - c2;
    if (t < nodeCnt) rowptr[nb + t] = start + excl;
    hist[t] = excl;
    __syncthreads();
    for (int i = t; i < cnt; i += 256) {
        unsigned p = pL[i];
        int pos = atomicAdd(&hist[p >> 16], 1);
        col[start + pos] = (int)(p & 0xFFFFu);
    }
}

// ---------------- tiled h = x @ W (64->64); bf16 in, bf16 out ----------------

__global__ __launch_bounds__(256) void k_mm64t(const unsigned short* __restrict__ xin,
                                               const float* __restrict__ W,
                                               const float* __restrict__ avs, const float* __restrict__ avd,
                                               unsigned short* __restrict__ h, float* __restrict__ as_,
                                               float* __restrict__ ad_) {
    __shared__ float xT[64 * 68];
    __shared__ float Wl[64 * 64];
    __shared__ float avl[64], adl[64];
    int t = threadIdx.x;
    int nbase = blockIdx.x * 64;
    for (int idx = t; idx < 64 * 64; idx += 256) Wl[idx] = W[idx];
    if (t < 64) { avl[t] = avs[t]; adl[t] = avd[t]; }
    for (int idx = t; idx < 64 * 64; idx += 256) {
        int n = idx / 64, k = idx - n * 64;
        int gn = nbase + n;
        if (gn >= NN) gn = NN - 1;
        xT[k * 68 + n] = bf2f(xin[gn * 64 + k]);
    }
    __syncthreads();
    int f0 = (t & 15) * 4;
    int n0 = (t >> 4) * 4;
    float a00=0,a01=0,a02=0,a03=0, a10=0,a11=0,a12=0,a13=0;
    float a20=0,a21=0,a22=0,a23=0, a30=0,a31=0,a32=0,a33=0;
#pragma unroll 4
    for (int k = 0; k < 64; k++) {
        float4 xv = *(const float4*)&xT[k * 68 + n0];
        float4 wv = *(const float4*)&Wl[k * 64 + f0];
        a00 += xv.x * wv.x; a01 += xv.x * wv.y; a02 += xv.x * wv.z; a03 += xv.x * wv.w;
        a10 += xv.y * wv.x; a11 += xv.y * wv.y; a12 += xv.y * wv.z; a13 += xv.y * wv.w;
        a20 += xv.z * wv.x; a21 += xv.z * wv.y; a22 += xv.z * wv.z; a23 += xv.z * wv.w;
        a30 += xv.w * wv.x; a31 += xv.w * wv.y; a32 += xv.w * wv.z; a33 += xv.w * wv.w;
    }
    float4 av = *(const float4*)&avl[f0];
    float4 dv = *(const float4*)&adl[f0];
    float vs[4], vd[4];
    vs[0] = a00*av.x + a01*av.y + a02*av.z + a03*av.w;
    vs[1] = a10*av.x + a11*av.y + a12*av.z + a13*av.w;
    vs[2] = a20*av.x + a21*av.y + a22*av.z + a23*av.w;
    vs[3] = a30*av.x + a31*av.y + a32*av.z + a33*av.w;
    vd[0] = a00*dv.x + a01*dv.y + a02*dv.z + a03*dv.w;
    vd[1] = a10*dv.x + a11*dv.y + a12*dv.z + a13*dv.w;
    vd[2] = a20*dv.x + a21*dv.y + a22*dv.z + a23*dv.w;
    vd[3] = a30*dv.x + a31*dv.y + a32*dv.z + a33*dv.w;
#pragma unroll
    for (int o = 1; o < 16; o <<= 1) {
#pragma unroll
        for (int ni = 0; ni < 4; ni++) {
            vs[ni] += __shfl_xor(vs[ni], o);
            vd[ni] += __shfl_xor(vd[ni], o);
        }
    }
    ushort4* h4 = (ushort4*)h;
    int nn0 = nbase + n0;
    float rows[4][4] = {{a00,a01,a02,a03},{a10,a11,a12,a13},{a20,a21,a22,a23},{a30,a31,a32,a33}};
#pragma unroll
    for (int ni = 0; ni < 4; ni++) {
        if (nn0 + ni < NN) {
            ushort4 pv;
            pv.x = f2bf(rows[ni][0]); pv.y = f2bf(rows[ni][1]);
            pv.z = f2bf(rows[ni][2]); pv.w = f2bf(rows[ni][3]);
            h4[(nn0 + ni) * 16 + (t & 15)] = pv;
            if ((t & 15) == 0) { as_[nn0 + ni] = vs[ni]; ad_[nn0 + ni] = vd[ni]; }
        }
    }
}

// ---------------- GAT aggregation, 64 features; register-prefetched rows ----------------
// R12 post-mortem: phase C was a serial (LDS -> 2 gathers) chain + ws staging had 4-way
// bank conflicts (2.6M cycles). Rows don't depend on softmax weights -> prefetch ALL rows
// into registers (16 predicated independent 8B gathers) BEFORE softmax; ws LDS deleted.

template <bool FUSE>
__global__ __launch_bounds__(256) void k_agg64(const unsigned short* __restrict__ h,
                                               const int* __restrict__ rowptr,
                                               const int* __restrict__ col, const float* __restrict__ as_,
                                               const float* __restrict__ ad_, const float* __restrict__ bias,
                                               unsigned short* __restrict__ out16,
                                               const float* __restrict__ W3, const float* __restrict__ a3s,
                                               const float* __restrict__ a3d,
                                               float* __restrict__ as3, float* __restrict__ ad3) {
    __shared__ float W3p[64 * 10];  // FUSE only; pad 8->10: 2-way conflicts only
    if constexpr (FUSE) {
        for (int idx = threadIdx.x; idx < 512; idx += 256)
            W3p[(idx >> 3) * 10 + (idx & 7)] = W3[idx];
        __syncthreads();  // uniform: before any divergence
    }
    int wid = threadIdx.x >> 6;
    int node = blockIdx.x * 4 + wid;   // NN = 12500*4: every wave valid
    int lane = threadIdx.x & 63;
    int rp0 = rowptr[node];
    int deg = rowptr[node + 1] - rp0;
    float adn = ad_[node];
    float zself = lrelu(as_[node] + adn);
    const uint2* hb2 = (const uint2*)h;   // row = 16 x uint2 (4 bf16 per uint2)
    int f = lane & 15, eg = lane >> 4;
    float4 acc = make_float4(0.f, 0.f, 0.f, 0.f);
    if (deg <= 64) {
        int s = 0;
        float z = -1e30f;
        if (lane < deg) {
            s = col[rp0 + lane];
            z = lrelu(as_[s] + adn);
        }
        // prefetch rows: edge e = k*4+eg, lane holds features 4f..4f+3 (8B). All independent.
        uint2 rowreg[16];
#pragma unroll
        for (int k = 0; k < 16; k++) {
            int e = k * 4 + eg;
            uint2 r = make_uint2(0u, 0u);
            if (e < deg) {
                int se = __shfl(s, e);
                r = hb2[se * 16 + f];
            }
            rowreg[k] = r;
        }
        // wave softmax
        float M = z;
#pragma unroll
        for (int o = 32; o; o >>= 1) M = fmaxf(M, __shfl_xor(M, o));
        M = fmaxf(M, zself);
        float ex = (lane < deg) ? __expf(z - M) : 0.f;
        float exs = __expf(zself - M);
        float sum = ex;
#pragma unroll
        for (int o = 32; o; o >>= 1) sum += __shfl_xor(sum, o);
        float inv = 1.f / (sum + exs);
        float wl = ex * inv;   // 0 beyond deg
        // phase C: pure register FMA (same edge order as before: k*4+eg ascending k)
#pragma unroll
        for (int k = 0; k < 16; k++) {
            int e = k * 4 + eg;
            if (e < deg) {
                float w = __shfl(wl, e);
                float2 lo = bf2x2(rowreg[k].x);
                float2 hi = bf2x2(rowreg[k].y);
                acc.x += w * lo.x;
                acc.y += w * lo.y;
                acc.z += w * hi.x;
                acc.w += w * hi.y;
            }
        }
        if (eg == 0) {
            float w0 = exs * inv;
            uint2 hv = hb2[node * 16 + f];
            float2 lo = bf2x2(hv.x);
            float2 hi = bf2x2(hv.y);
            acc.x += w0 * lo.x;
            acc.y += w0 * lo.y;
            acc.z += w0 * hi.x;
            acc.w += w0 * hi.y;
        }
    } else {  // rare fallback: online softmax + direct gathers
        float m = -1e30f, l = 0.f;
        for (int i = lane; i < deg; i += 64) {
            float z = lrelu(as_[col[rp0 + i]] + adn);
            float mn = fmaxf(m, z);
            l = l * __expf(m - mn) + __expf(z - mn);
            m = mn;
        }
        if (lane == 0) {
            float mn = fmaxf(m, zself);
            l = l * __expf(m - mn) + __expf(zself - mn);
            m = mn;
        }
#pragma unroll
        for (int o = 32; o; o >>= 1) {
            float mo = __shfl_xor(m, o), lo = __shfl_xor(l, o);
            float mn = fmaxf(m, mo);
            l = l * __expf(m - mn) + lo * __expf(mo - mn);
            m = mn;
        }
        float Em = m;
        float inv = 1.f / l;
        for (int base = 0; base < deg; base += 4) {
            int i = base + eg;
            if (i < deg) {
                int sv = col[rp0 + i];
                float al = __expf(lrelu(as_[sv] + adn) - Em) * inv;
                uint2 hv = hb2[sv * 16 + f];
                float2 lo = bf2x2(hv.x);
                float2 hi = bf2x2(hv.y);
                acc.x += al * lo.x;
                acc.y += al * lo.y;
                acc.z += al * hi.x;
                acc.w += al * hi.y;
            }
        }
        if (eg == 0) {
            float al = __expf(zself - Em) * inv;
            uint2 hv = hb2[node * 16 + f];
            float2 lo = bf2x2(hv.x);
            float2 hi = bf2x2(hv.y);
            acc.x += al * lo.x;
            acc.y += al * lo.y;
            acc.z += al * hi.x;
            acc.w += al * hi.y;
        }
    }
#pragma unroll
    for (int o = 16; o <= 32; o <<= 1) {    // after this, ALL lanes hold the reduced row
        acc.x += __shfl_xor(acc.x, o);
        acc.y += __shfl_xor(acc.y, o);
        acc.z += __shfl_xor(acc.z, o);
        acc.w += __shfl_xor(acc.w, o);
    }
    float4 bv = ((const float4*)bias)[f];
    float r0 = fmaxf(acc.x + bv.x, 0.f);
    float r1 = fmaxf(acc.y + bv.y, 0.f);
    float r2 = fmaxf(acc.z + bv.z, 0.f);
    float r3 = fmaxf(acc.w + bv.w, 0.f);
    if constexpr (!FUSE) {
        if (eg == 0) {
            ushort4 pv;
            pv.x = f2bf(r0); pv.y = f2bf(r1); pv.z = f2bf(r2); pv.w = f2bf(r3);
            ((ushort4*)out16)[node * 16 + f] = pv;
        }
    } else {
        // h3[j] = sum_k row2[k] * W3[k][j]; eg owns outputs (2eg, 2eg+1); lane f owns k = 4f..4f+3
        int j0 = eg * 2;
        int kb = f * 4;
        float p0 = 0.f, p1 = 0.f;
#pragma unroll
        for (int i = 0; i < 4; i++) {
            float2 w = *(const float2*)&W3p[(kb + i) * 10 + j0];
            float rv = (i == 0) ? r0 : (i == 1) ? r1 : (i == 2) ? r2 : r3;
            p0 += rv * w.x;
            p1 += rv * w.y;
        }
#pragma unroll
        for (int o = 1; o < 16; o <<= 1) {   // reduce over f (within 16-lane group)
            p0 += __shfl_xor(p0, o);
            p1 += __shfl_xor(p1, o);
        }
        float vs = p0 * a3s[j0] + p1 * a3s[j0 + 1];
        float vd = p0 * a3d[j0] + p1 * a3d[j0 + 1];
        vs += __shfl_xor(vs, 16); vs += __shfl_xor(vs, 32);
        vd += __shfl_xor(vd, 16); vd += __shfl_xor(vd, 32);
        if (lane == 0) { as3[node] = vs; ad3[node] = vd; }
        if (f == 0) {
            ushort2 pv;
            pv.x = f2bf(p0); pv.y = f2bf(p1);
            ((ushort2*)out16)[node * 4 + eg] = pv;
        }
    }
}

// ---------------- layer-3 aggregation (register-prefetched, no LDS) ----------------

__global__ __launch_bounds__(256) void k_agg8(const unsigned short* __restrict__ h,
                                              const int* __restrict__ rowptr,
                                              const int* __restrict__ col, const float* __restrict__ as_,
                                              const float* __restrict__ ad_, const float* __restrict__ bias,
                                              float* __restrict__ out) {
    int wid = threadIdx.x >> 6;
    int node = blockIdx.x * 4 + wid;
    int lane = threadIdx.x & 63;
    int rp0 = rowptr[node];
    int deg = rowptr[node + 1] - rp0;
    float adn = ad_[node];
    float zself = lrelu(as_[node] + adn);
    const unsigned* h1 = (const unsigned*)h;   // row = 4 uints (2 bf16 each)
    int f = lane & 3, eg = lane >> 2;          // 16 edges in parallel, 4B per lane
    float2 acc = make_float2(0.f, 0.f);
    if (deg <= 64) {
        int s = 0;
        float z = -1e30f;
        if (lane < deg) {
            s = col[rp0 + lane];
            z = lrelu(as_[s] + adn);
        }
        unsigned rowreg[4];
#pragma unroll
        for (int k = 0; k < 4; k++) {
            int e = k * 16 + eg;
            unsigned r = 0u;
            if (e < deg) {
                int se = __shfl(s, e);
                r = h1[se * 4 + f];
            }
            rowreg[k] = r;
        }
        float M = z;
#pragma unroll
        for (int o = 32; o; o >>= 1) M = fmaxf(M, __shfl_xor(M, o));
        M = fmaxf(M, zself);
        float ex = (lane < deg) ? __expf(z - M) : 0.f;
        float exs = __expf(zself - M);
        float sum = ex;
#pragma unroll
        for (int o = 32; o; o >>= 1) sum += __shfl_xor(sum, o);
        float inv = 1.f / (sum + exs);
        float wl = ex * inv;
#pragma unroll
        for (int k = 0; k < 4; k++) {
            int e = k * 16 + eg;
            if (e < deg) {
                float w = __shfl(wl, e);
                float2 hv = bf2x2(rowreg[k]);
                acc.x += w * hv.x;
                acc.y += w * hv.y;
            }
        }
        if (eg == 0) {
            float w0 = exs * inv;
            float2 hv = bf2x2(h1[node * 4 + f]);
            acc.x += w0 * hv.x;
            acc.y += w0 * hv.y;
        }
    } else {
        float m = -1e30f, l = 0.f;
        for (int i = lane; i < deg; i += 64) {
            float z = lrelu(as_[col[rp0 + i]] + adn);
            float mn = fmaxf(m, z);
            l = l * __expf(m - mn) + __expf(z - mn);
            m = mn;
        }
        if (lane == 0) {
            float mn = fmaxf(m, zself);
            l = l * __expf(m - mn) + __expf(zself - mn);
            m = mn;
        }
#pragma unroll
        for (int o = 32; o; o >>= 1) {
            float mo = __shfl_xor(m, o), lo = __shfl_xor(l, o);
            float mn = fmaxf(m, mo);
            l = l * __expf(m - mn) + lo * __expf(mo - mn);
            m = mn;
        }
        float Em = m;
        float inv = 1.f / l;
        for (int base = 0; base < deg; base += 16) {
            int i = base + eg;
            if (i < deg) {
                int sv = col[rp0 + i];
                float al = __expf(lrelu(as_[sv] + adn) - Em) * inv;
                float2 hv = bf2x2(h1[sv * 4 + f]);
                acc.x += al * hv.x;
                acc.y += al * hv.y;
            }
        }
        if (eg == 0) {
            float al = __expf(zself - Em) * inv;
            float2 hv = bf2x2(h1[node * 4 + f]);
            acc.x += al * hv.x;
            acc.y += al * hv.y;
        }
    }
#pragma unroll
    for (int o = 4; o <= 32; o <<= 1) {
        acc.x += __shfl_xor(acc.x, o);
        acc.y += __shfl_xor(acc.y, o);
    }
    if (eg == 0) {
        float2 bv = ((const float2*)bias)[f];
        float2 o2;
        o2.x = fmaxf(acc.x + bv.x, 0.f);
        o2.y = fmaxf(acc.y + bv.y, 0.f);
        ((float2*)out)[node * 4 + f] = o2;
    }
}

// ---------------- k9: mean-pool + sigmoid (196 blocks, done-ticket; R9/R10-verified) ----------------

__global__ __launch_bounds__(256) void k9_poolfinal(const float* __restrict__ h3, const int* __restrict__ batch,
                                                    float* __restrict__ pool, float* __restrict__ cntf,
                                                    float* __restrict__ out) {
    __shared__ float pl[GG * CC + GG];
    __shared__ int lastFlag;
    int t = threadIdx.x;
    for (int idx = t; idx < GG * CC + GG; idx += 256) pl[idx] = 0.f;
    __syncthreads();
    int node = blockIdx.x * 256 + t;
    if (node < NN) {
        int g = batch[node];
#pragma unroll
        for (int c = 0; c < CC; c++) atomicAdd(&pl[g * CC + c], h3[node * CC + c]);
        atomicAdd(&pl[GG * CC + g], 1.0f);
    }
    __syncthreads();
    for (int idx = t; idx < GG * CC + GG; idx += 256) {
        float v = pl[idx];
        if (idx < GG * CC)
            atomicAdd(&pool[idx], v);
        else
            atomicAdd(&cntf[idx - GG * CC], v);
    }
    __syncthreads();
    if (t == 0) {
        __threadfence();
        unsigned r = __hip_atomic_fetch_add(&g_done, 1u, __ATOMIC_ACQ_REL, __HIP_MEMORY_SCOPE_AGENT);
        lastFlag = (r == (unsigned)(NBKT - 1));
    }
    __syncthreads();
    if (lastFlag) {
        __threadfence();
        for (int i = t; i < GG * CC; i += 256) {
            int g = i >> 3;
            float c = __hip_atomic_load(&cntf[g], __ATOMIC_RELAXED, __HIP_MEMORY_SCOPE_AGENT);
            float p = __hip_atomic_load(&pool[i], __ATOMIC_RELAXED, __HIP_MEMORY_SCOPE_AGENT);
            float v = p / fmaxf(c, 1.0f);
            out[i] = 1.0f / (1.0f + __expf(-v));
        }
        if (t == 0)
            __hip_atomic_store(&g_done, 0u, __ATOMIC_RELAXED, __HIP_MEMORY_SCOPE_AGENT);
    }
}

// ---------------- launch ----------------

extern "C" void kernel_launch(void* const* d_in, const int* in_sizes, int n_in,
                              void* d_out, int out_size, void* d_ws, size_t ws_size,
                              hipStream_t stream) {
    const float* x   = (const float*)d_in[0];
    const int*   ei  = (const int*)d_in[1];
    const int*   bat = (const int*)d_in[3];
    const float* W1  = (const float*)d_in[4];
    const float* a1s = (const float*)d_in[5];
    const float* a1d = (const float*)d_in[6];
    const float* b1  = (const float*)d_in[7];
    const float* W2  = (const float*)d_in[8];
    const float* a2s = (const float*)d_in[9];
    const float* a2d = (const float*)d_in[10];
    const float* b2  = (const float*)d_in[11];
    const float* W3  = (const float*)d_in[12];
    const float* a3s = (const float*)d_in[13];
    const float* a3d = (const float*)d_in[14];
    const float* b3  = (const float*)d_in[15];
    float* out = (float*)d_out;

    // workspace carve-up
    float* fb = (float*)d_ws;
    unsigned short* hA16 = (unsigned short*)fb;              // N*64 bf16 (N*32 floats)
    unsigned short* hB16 = (unsigned short*)(fb + NN * 32);  // N*64 bf16
    unsigned short* h316 = (unsigned short*)(fb + NN * 64);  // N*8 bf16 (N*4 floats)
    float* h3b  = fb + NN * 64 + NN * 4;                     // N*8 f32
    float* as_  = h3b + NN * 8;                              // N
    float* ad_  = as_ + NN;                                  // N
    float* as3  = ad_ + NN;                                  // N
    float* ad3  = as3 + NN;                                  // N
    int* rowptr = (int*)(ad3 + NN);                          // N+1
    int* col    = rowptr + NN + 1;                           // E
    int* G      = col + EE;                                  // NCHK*NBKT
    int* offs   = G + NCHK * NBKT;                           // NCHK*NBKT
    int* bT     = offs + NCHK * NBKT;                        // 256 (padded)
    unsigned* pairs = (unsigned*)(bT + 256);                 // E
    float* pool = (float*)(pairs + EE);                      // G*C
    float* cntf = pool + GG * CC;                            // G

    const int NB64 = (NN + 63) / 64;     // 782 (= NCHK)

    const int* srcE = ei;
    const int* dstE = ei + EE;

    k0_mm11_hist<<<NB64, 256, 0, stream>>>(x, W1, a1s, a1d, hA16, as_, ad_, dstE, G);
    k1_scan<<<NBKT, 256, 0, stream>>>(G, offs, bT, pool, cntf, rowptr);
    k2_part<<<NCHK, 256, 0, stream>>>(srcE, dstE, offs, bT, pairs);
    k3_sort<<<NBKT, 256, 0, stream>>>(pairs, bT, col, rowptr);

    k_agg64<false><<<NB4G, 256, 0, stream>>>(hA16, rowptr, col, as_, ad_, b1, hB16,
                                             nullptr, nullptr, nullptr, nullptr, nullptr);
    k_mm64t<<<NB64, 256, 0, stream>>>(hB16, W2, a2s, a2d, hA16, as_, ad_);
    k_agg64<true><<<NB4G, 256, 0, stream>>>(hA16, rowptr, col, as_, ad_, b2, h316,
                                            W3, a3s, a3d, as3, ad3);
    k_agg8<<<NB4G, 256, 0, stream>>>(h316, rowptr, col, as3, ad3, b3, h3b);
    k9_poolfinal<<<NBKT, 256, 0, stream>>>(h3b, bat, pool, cntf, out);
}